// Round 3
// baseline (894.203 us; speedup 1.0000x reference)
//
#include <hip/hip_runtime.h>
#include <hip/hip_bf16.h>

#define EPSV 1e-5f

typedef __attribute__((ext_vector_type(8))) short bf16x8;
typedef __attribute__((ext_vector_type(4))) short bf16x4s;
typedef __attribute__((ext_vector_type(4))) float f32x4;

static __device__ __forceinline__ short f2bf(float f) {
  return __builtin_bit_cast(short, __float2bfloat16(f));
}
static __device__ __forceinline__ float bf2f(short s) {
  return __builtin_bit_cast(float, ((unsigned)(unsigned short)s) << 16);
}

// ---------------- node pipeline (unchanged this round) ----------------
__global__ __launch_bounds__(192) void node_kernel(
    const float* __restrict__ node_feats, const float* __restrict__ cond,
    const float* __restrict__ W_cond, const float* __restrict__ b_cond,
    const float* __restrict__ W_film, const float* __restrict__ b_film,
    float* __restrict__ h, int N)
{
  __shared__ __align__(16) float cond_lds[16][256];
  __shared__ __align__(16) float nf_lds[16][128];
  __shared__ __align__(16) float gb_lds[16][128];
  const int t = threadIdx.x;
  const int n0 = blockIdx.x * 16;
  const int rows = min(16, N - n0);

  {
    const float4* c4 = (const float4*)(cond + (size_t)n0 * 256);
    float4* sc = (float4*)&cond_lds[0][0];
    const int climit = rows * 64;
    for (int i = t; i < 16 * 64; i += 192)
      sc[i] = (i < climit) ? c4[i] : make_float4(0.f, 0.f, 0.f, 0.f);
    const float4* n4 = (const float4*)(node_feats + (size_t)n0 * 128);
    float4* sn = (float4*)&nf_lds[0][0];
    const int nlimit = rows * 32;
    for (int i = t; i < 16 * 32; i += 192)
      sn[i] = (i < nlimit) ? n4[i] : make_float4(0.f, 0.f, 0.f, 0.f);
  }
  __syncthreads();

  float acc[16];
  if (t < 128) {
    const float binit = b_cond[t] + (t < 64 ? 1.0f : 0.0f);
#pragma unroll
    for (int j = 0; j < 16; ++j) acc[j] = binit;
    for (int k4 = 0; k4 < 64; ++k4) {
      const float w0 = W_cond[(k4 * 4 + 0) * 128 + t];
      const float w1 = W_cond[(k4 * 4 + 1) * 128 + t];
      const float w2 = W_cond[(k4 * 4 + 2) * 128 + t];
      const float w3 = W_cond[(k4 * 4 + 3) * 128 + t];
#pragma unroll
      for (int j = 0; j < 16; ++j) {
        const float4 v = *(const float4*)&cond_lds[j][k4 * 4];
        acc[j] = fmaf(v.w, w3, fmaf(v.z, w2, fmaf(v.y, w1, fmaf(v.x, w0, acc[j]))));
      }
    }
#pragma unroll
    for (int j = 0; j < 16; ++j) gb_lds[j][t] = acc[j];
  } else {
    const int c = t - 128;
    const float binit = b_film[c];
#pragma unroll
    for (int j = 0; j < 16; ++j) acc[j] = binit;
    for (int k4 = 0; k4 < 32; ++k4) {
      const float w0 = W_film[(k4 * 4 + 0) * 64 + c];
      const float w1 = W_film[(k4 * 4 + 1) * 64 + c];
      const float w2 = W_film[(k4 * 4 + 2) * 64 + c];
      const float w3 = W_film[(k4 * 4 + 3) * 64 + c];
#pragma unroll
      for (int j = 0; j < 16; ++j) {
        const float4 v = *(const float4*)&nf_lds[j][k4 * 4];
        acc[j] = fmaf(v.w, w3, fmaf(v.z, w2, fmaf(v.y, w1, fmaf(v.x, w0, acc[j]))));
      }
    }
#pragma unroll
    for (int j = 0; j < 16; ++j) {
      float s = acc[j];
      float q = acc[j] * acc[j];
#pragma unroll
      for (int off = 32; off >= 1; off >>= 1) {
        s += __shfl_xor(s, off, 64);
        q += __shfl_xor(q, off, 64);
      }
      const float mu = s * (1.0f / 64.0f);
      const float var = q * (1.0f / 64.0f) - mu * mu;
      acc[j] = (acc[j] - mu) * rsqrtf(var + EPSV);
    }
  }
  __syncthreads();
  if (t >= 128) {
    const int c = t - 128;
#pragma unroll
    for (int j = 0; j < 16; ++j) {
      if (j < rows) {
        const float g = gb_lds[j][c];
        const float b = gb_lds[j][64 + c];
        const float hv = fmaf(g, acc[j], b);
        h[(size_t)(n0 + j) * 64 + c] = fmaxf(hv, 0.0f);
      }
    }
  }
}

// ---------------- phase 1: P = tanh(edge_feats @ W_edge + b_edge), bf16 ----------------
// Streaming MFMA tile, fully coalesced (no mirror gather here).
__global__ __launch_bounds__(256) void edge_param_kernel(
    const float* __restrict__ edge_feats,
    const float* __restrict__ W_edge, const float* __restrict__ b_edge,
    short* __restrict__ P, int E)
{
  const int lane = threadIdx.x & 63;
  const int r16  = lane & 15;
  const int kb   = lane >> 4;
  const int gwid   = (int)((blockIdx.x * blockDim.x + threadIdx.x) >> 6);
  const int nwaves = (int)((gridDim.x * blockDim.x) >> 6);

  bf16x8 bfr[4][2];
#pragma unroll
  for (int nb = 0; nb < 4; ++nb)
#pragma unroll
    for (int ks = 0; ks < 2; ++ks)
#pragma unroll
      for (int j = 0; j < 8; ++j) {
        const int k = ks * 32 + kb * 8 + j;
        bfr[nb][ks][j] = f2bf(W_edge[k * 64 + nb * 16 + r16]);
      }
  float bb[4];
#pragma unroll
  for (int nb = 0; nb < 4; ++nb) bb[nb] = b_edge[nb * 16 + r16];

  const int ntiles = (E + 15) >> 4;
  for (int t = gwid; t < ntiles; t += nwaves) {
    const int e0 = t << 4;
    const int er = min(e0 + r16, E - 1);
    const float* arow = edge_feats + (size_t)er * 64 + kb * 8;
    const f32x4 a0 = *(const f32x4*)(arow);
    const f32x4 a1 = *(const f32x4*)(arow + 4);
    const f32x4 a2 = *(const f32x4*)(arow + 32);
    const f32x4 a3 = *(const f32x4*)(arow + 36);

    bf16x8 af0, af1;
#pragma unroll
    for (int j = 0; j < 4; ++j) {
      af0[j]     = f2bf(a0[j]);
      af0[j + 4] = f2bf(a1[j]);
      af1[j]     = f2bf(a2[j]);
      af1[j + 4] = f2bf(a3[j]);
    }

    f32x4 c[4];
#pragma unroll
    for (int nb = 0; nb < 4; ++nb) c[nb] = (f32x4){0.f, 0.f, 0.f, 0.f};
#pragma unroll
    for (int nb = 0; nb < 4; ++nb) {
      c[nb] = __builtin_amdgcn_mfma_f32_16x16x32_bf16(af0, bfr[nb][0], c[nb], 0, 0, 0);
      c[nb] = __builtin_amdgcn_mfma_f32_16x16x32_bf16(af1, bfr[nb][1], c[nb], 0, 0, 0);
    }

    // C/D: col = r16 (n = nb*16+r16), row = kb*4 + j  -> edge e0 + kb*4 + j
#pragma unroll
    for (int j = 0; j < 4; ++j) {
      const int row = e0 + kb * 4 + j;
      if (row < E) {
#pragma unroll
        for (int nb = 0; nb < 4; ++nb) {
          const float s = c[nb][j] + bb[nb];
          const float p = 1.0f - 2.0f / (__expf(2.0f * s) + 1.0f);   // tanh
          P[(size_t)row * 64 + nb * 16 + r16] = f2bf(p);
        }
      }
    }
  }
}

// ---------------- phase 2: out[dst] += h[src] * P[mirror] * ew ----------------
// 8 edges per wave-iteration (2 groups of 4), 16 lanes per edge, 4 ch/lane.
__global__ __launch_bounds__(256) void scatter_kernel(
    const short* __restrict__ P, const float* __restrict__ h,
    const float* __restrict__ ew,
    const int* __restrict__ src, const int* __restrict__ dst,
    const int* __restrict__ mirror,
    float* __restrict__ out, int E)
{
  const int lane = threadIdx.x & 63;
  const int g = lane >> 4;        // edge slot within group of 4
  const int r = lane & 15;        // channel quad
  const int wid = (int)((blockIdx.x * blockDim.x + threadIdx.x) >> 6);
  const int nw  = (int)((gridDim.x * blockDim.x) >> 6);
  const int niter = (E + 7) >> 3;

  for (int it = wid; it < niter; it += nw) {
    const int eA = it * 8 + g;
    const int eB = eA + 4;
    const bool vA = eA < E, vB = eB < E;
    const int cA = vA ? eA : 0, cB = vB ? eB : 0;
    const int mA = mirror[cA], sA = src[cA], dA = dst[cA];
    const int mB = mirror[cB], sB = src[cB], dB = dst[cB];
    const float wA = ew[cA], wB = ew[cB];

    const bf16x4s pA = *(const bf16x4s*)(P + (size_t)mA * 64 + r * 4);
    const bf16x4s pB = *(const bf16x4s*)(P + (size_t)mB * 64 + r * 4);
    const f32x4  hA = *(const f32x4*)(h + (size_t)sA * 64 + r * 4);
    const f32x4  hB = *(const f32x4*)(h + (size_t)sB * 64 + r * 4);

    if (vA) {
      float* o = out + (size_t)dA * 64 + r * 4;
      atomicAdd(o + 0, bf2f(pA[0]) * wA * hA[0]);
      atomicAdd(o + 1, bf2f(pA[1]) * wA * hA[1]);
      atomicAdd(o + 2, bf2f(pA[2]) * wA * hA[2]);
      atomicAdd(o + 3, bf2f(pA[3]) * wA * hA[3]);
    }
    if (vB) {
      float* o = out + (size_t)dB * 64 + r * 4;
      atomicAdd(o + 0, bf2f(pB[0]) * wB * hB[0]);
      atomicAdd(o + 1, bf2f(pB[1]) * wB * hB[1]);
      atomicAdd(o + 2, bf2f(pB[2]) * wB * hB[2]);
      atomicAdd(o + 3, bf2f(pB[3]) * wB * hB[3]);
    }
  }
}

// ---------------- fallback (R2 fused) if ws too small ----------------
__global__ __launch_bounds__(256) void edge_kernel_fused(
    const float* __restrict__ edge_feats, const float* __restrict__ edge_weights,
    const int* __restrict__ src, const int* __restrict__ dst,
    const int* __restrict__ mirror,
    const float* __restrict__ W_edge, const float* __restrict__ b_edge,
    const float* __restrict__ h, float* __restrict__ out, int E)
{
  const int lane = threadIdx.x & 63;
  const int r16  = lane & 15;
  const int kb   = lane >> 4;
  const int gwid   = (int)((blockIdx.x * blockDim.x + threadIdx.x) >> 6);
  const int nwaves = (int)((gridDim.x * blockDim.x) >> 6);
  bf16x8 bfr[4][2];
#pragma unroll
  for (int nb = 0; nb < 4; ++nb)
#pragma unroll
    for (int ks = 0; ks < 2; ++ks)
#pragma unroll
      for (int j = 0; j < 8; ++j) {
        const int k = ks * 32 + kb * 8 + j;
        bfr[nb][ks][j] = f2bf(W_edge[k * 64 + nb * 16 + r16]);
      }
  float bb[4];
#pragma unroll
  for (int nb = 0; nb < 4; ++nb) bb[nb] = b_edge[nb * 16 + r16];
  const int ntiles = (E + 15) >> 4;
  for (int t = gwid; t < ntiles; t += nwaves) {
    const int e0 = t << 4;
    const int er = min(e0 + r16, E - 1);
    const int sv = src[er];
    const int dv = dst[er];
    const float wv = (e0 + r16 < E) ? edge_weights[er] : 0.0f;
    const int mv = mirror[er];
    const float* arow = edge_feats + (size_t)mv * 64 + kb * 8;
    const f32x4 a0 = *(const f32x4*)(arow);
    const f32x4 a1 = *(const f32x4*)(arow + 4);
    const f32x4 a2 = *(const f32x4*)(arow + 32);
    const f32x4 a3 = *(const f32x4*)(arow + 36);
    int dj[4]; float ewj[4]; float hv[4][4];
#pragma unroll
    for (int j = 0; j < 4; ++j) {
      const int row = kb * 4 + j;
      const int sj = __shfl(sv, row, 64);
      dj[j]  = __shfl(dv, row, 64);
      ewj[j] = __shfl(wv, row, 64);
      const float* hrow = h + (size_t)sj * 64 + r16;
#pragma unroll
      for (int nb = 0; nb < 4; ++nb) hv[j][nb] = hrow[nb * 16];
    }
    bf16x8 af0, af1;
#pragma unroll
    for (int j = 0; j < 4; ++j) {
      af0[j]     = f2bf(a0[j]);
      af0[j + 4] = f2bf(a1[j]);
      af1[j]     = f2bf(a2[j]);
      af1[j + 4] = f2bf(a3[j]);
    }
    f32x4 c[4];
#pragma unroll
    for (int nb = 0; nb < 4; ++nb) c[nb] = (f32x4){0.f, 0.f, 0.f, 0.f};
#pragma unroll
    for (int nb = 0; nb < 4; ++nb) {
      c[nb] = __builtin_amdgcn_mfma_f32_16x16x32_bf16(af0, bfr[nb][0], c[nb], 0, 0, 0);
      c[nb] = __builtin_amdgcn_mfma_f32_16x16x32_bf16(af1, bfr[nb][1], c[nb], 0, 0, 0);
    }
#pragma unroll
    for (int j = 0; j < 4; ++j) {
#pragma unroll
      for (int nb = 0; nb < 4; ++nb) {
        const float s = c[nb][j] + bb[nb];
        const float p = (1.0f - 2.0f / (__expf(2.0f * s) + 1.0f)) * ewj[j];
        atomicAdd(&out[(size_t)dj[j] * 64 + nb * 16 + r16], p * hv[j][nb]);
      }
    }
  }
}

extern "C" void kernel_launch(void* const* d_in, const int* in_sizes, int n_in,
                              void* d_out, int out_size, void* d_ws, size_t ws_size,
                              hipStream_t stream) {
  const float* node_feats   = (const float*)d_in[0];
  const float* edge_feats   = (const float*)d_in[1];
  const float* cond         = (const float*)d_in[2];
  const float* edge_weights = (const float*)d_in[3];
  const int*   src          = (const int*)d_in[4];
  const int*   dst          = (const int*)d_in[5];
  const int*   mirror       = (const int*)d_in[6];
  const float* W_edge       = (const float*)d_in[7];
  const float* b_edge       = (const float*)d_in[8];
  const float* W_cond       = (const float*)d_in[9];
  const float* b_cond       = (const float*)d_in[10];
  const float* W_film       = (const float*)d_in[11];
  const float* b_film       = (const float*)d_in[12];
  const int N = in_sizes[0] / 128;
  const int E = in_sizes[4];

  float* h = (float*)d_ws;                                  // N*64 f32 = 12.8 MB
  const size_t hbytes = (size_t)N * 64 * sizeof(float);
  short* P = (short*)((char*)d_ws + hbytes);                // E*64 bf16 = 102.4 MB
  const size_t needed = hbytes + (size_t)E * 64 * sizeof(short);

  hipMemsetAsync(d_out, 0, (size_t)out_size * sizeof(float), stream);
  node_kernel<<<(N + 15) / 16, 192, 0, stream>>>(
      node_feats, cond, W_cond, b_cond, W_film, b_film, h, N);

  if (ws_size >= needed) {
    edge_param_kernel<<<2048, 256, 0, stream>>>(edge_feats, W_edge, b_edge, P, E);
    scatter_kernel<<<2048, 256, 0, stream>>>(P, h, edge_weights, src, dst, mirror,
                                             (float*)d_out, E);
  } else {
    edge_kernel_fused<<<2048, 256, 0, stream>>>(
        edge_feats, edge_weights, src, dst, mirror, W_edge, b_edge, h,
        (float*)d_out, E);
  }
}

// Round 4
// 434.650 us; speedup vs baseline: 2.0573x; 2.0573x over previous
//
#include <hip/hip_runtime.h>
#include <hip/hip_bf16.h>

#define EPSV 1e-5f

typedef __attribute__((ext_vector_type(8))) short bf16x8;
typedef __attribute__((ext_vector_type(4))) float f32x4;

static __device__ __forceinline__ short f2bf(float f) {
  return __builtin_bit_cast(short, __float2bfloat16(f));
}

// ---------------- node pipeline (unchanged) ----------------
__global__ __launch_bounds__(192) void node_kernel(
    const float* __restrict__ node_feats, const float* __restrict__ cond,
    const float* __restrict__ W_cond, const float* __restrict__ b_cond,
    const float* __restrict__ W_film, const float* __restrict__ b_film,
    float* __restrict__ h, int N)
{
  __shared__ __align__(16) float cond_lds[16][256];
  __shared__ __align__(16) float nf_lds[16][128];
  __shared__ __align__(16) float gb_lds[16][128];
  const int t = threadIdx.x;
  const int n0 = blockIdx.x * 16;
  const int rows = min(16, N - n0);

  {
    const float4* c4 = (const float4*)(cond + (size_t)n0 * 256);
    float4* sc = (float4*)&cond_lds[0][0];
    const int climit = rows * 64;
    for (int i = t; i < 16 * 64; i += 192)
      sc[i] = (i < climit) ? c4[i] : make_float4(0.f, 0.f, 0.f, 0.f);
    const float4* n4 = (const float4*)(node_feats + (size_t)n0 * 128);
    float4* sn = (float4*)&nf_lds[0][0];
    const int nlimit = rows * 32;
    for (int i = t; i < 16 * 32; i += 192)
      sn[i] = (i < nlimit) ? n4[i] : make_float4(0.f, 0.f, 0.f, 0.f);
  }
  __syncthreads();

  float acc[16];
  if (t < 128) {
    const float binit = b_cond[t] + (t < 64 ? 1.0f : 0.0f);
#pragma unroll
    for (int j = 0; j < 16; ++j) acc[j] = binit;
    for (int k4 = 0; k4 < 64; ++k4) {
      const float w0 = W_cond[(k4 * 4 + 0) * 128 + t];
      const float w1 = W_cond[(k4 * 4 + 1) * 128 + t];
      const float w2 = W_cond[(k4 * 4 + 2) * 128 + t];
      const float w3 = W_cond[(k4 * 4 + 3) * 128 + t];
#pragma unroll
      for (int j = 0; j < 16; ++j) {
        const float4 v = *(const float4*)&cond_lds[j][k4 * 4];
        acc[j] = fmaf(v.w, w3, fmaf(v.z, w2, fmaf(v.y, w1, fmaf(v.x, w0, acc[j]))));
      }
    }
#pragma unroll
    for (int j = 0; j < 16; ++j) gb_lds[j][t] = acc[j];
  } else {
    const int c = t - 128;
    const float binit = b_film[c];
#pragma unroll
    for (int j = 0; j < 16; ++j) acc[j] = binit;
    for (int k4 = 0; k4 < 32; ++k4) {
      const float w0 = W_film[(k4 * 4 + 0) * 64 + c];
      const float w1 = W_film[(k4 * 4 + 1) * 64 + c];
      const float w2 = W_film[(k4 * 4 + 2) * 64 + c];
      const float w3 = W_film[(k4 * 4 + 3) * 64 + c];
#pragma unroll
      for (int j = 0; j < 16; ++j) {
        const float4 v = *(const float4*)&nf_lds[j][k4 * 4];
        acc[j] = fmaf(v.w, w3, fmaf(v.z, w2, fmaf(v.y, w1, fmaf(v.x, w0, acc[j]))));
      }
    }
#pragma unroll
    for (int j = 0; j < 16; ++j) {
      float s = acc[j];
      float q = acc[j] * acc[j];
#pragma unroll
      for (int off = 32; off >= 1; off >>= 1) {
        s += __shfl_xor(s, off, 64);
        q += __shfl_xor(q, off, 64);
      }
      const float mu = s * (1.0f / 64.0f);
      const float var = q * (1.0f / 64.0f) - mu * mu;
      acc[j] = (acc[j] - mu) * rsqrtf(var + EPSV);
    }
  }
  __syncthreads();
  if (t >= 128) {
    const int c = t - 128;
#pragma unroll
    for (int j = 0; j < 16; ++j) {
      if (j < rows) {
        const float g = gb_lds[j][c];
        const float b = gb_lds[j][64 + c];
        const float hv = fmaf(g, acc[j], b);
        h[(size_t)(n0 + j) * 64 + c] = fmaxf(hv, 0.0f);
      }
    }
  }
}

// ---------------- counting sort by dst ----------------
__global__ __launch_bounds__(256) void hist_kernel(
    const int* __restrict__ dst, int* __restrict__ cnt, int E)
{
  const int stride = gridDim.x * blockDim.x;
  for (int e = blockIdx.x * blockDim.x + threadIdx.x; e < E; e += stride)
    atomicAdd(&cnt[dst[e]], 1);
}

__global__ __launch_bounds__(1024) void scan_kernel(
    const int* __restrict__ cnt, int* __restrict__ binst,
    int* __restrict__ cursor, int N)
{
  __shared__ int wsum[16];
  const int t = threadIdx.x;
  const int lane = t & 63, w = t >> 6;
  const int chunk = (N + 1023) >> 10;
  const int lo = min(t * chunk, N), hi = min(lo + chunk, N);
  int s = 0;
  for (int i = lo; i < hi; ++i) s += cnt[i];
  int ps = s;  // inclusive wave scan
#pragma unroll
  for (int off = 1; off < 64; off <<= 1) {
    const int v = __shfl_up(ps, off, 64);
    if (lane >= off) ps += v;
  }
  if (lane == 63) wsum[w] = ps;
  __syncthreads();
  if (t == 0) {
    int run = 0;
    for (int i = 0; i < 16; ++i) { const int v = wsum[i]; wsum[i] = run; run += v; }
  }
  __syncthreads();
  int base = wsum[w] + (ps - s);   // exclusive prefix for this thread's chunk
  for (int i = lo; i < hi; ++i) {
    const int c = cnt[i];
    binst[i] = base;
    cursor[i] = base;
    base += c;
  }
}

__global__ __launch_bounds__(256) void fill_kernel(
    const int* __restrict__ dst, int* __restrict__ cursor,
    int* __restrict__ eidx, int E)
{
  const int stride = gridDim.x * blockDim.x;
  for (int e = blockIdx.x * blockDim.x + threadIdx.x; e < E; e += stride) {
    const int pos = atomicAdd(&cursor[dst[e]], 1);
    eidx[pos] = e;
  }
}

// ---------------- fused gather-MFMA-accumulate, one wave per dst ----------------
// For each dst d: out[d] = sum over its edges of tanh(ef[mirror[e]]@W+b)*ew[e]*h[src[e]]
// MFMA tile = 16 edges of the bin (padded, ew=0) x 64 ch. Rows share dst ->
// reduce C across rows (in-lane over j, cross-lane shfl_xor over kb), store once.
__global__ __launch_bounds__(256) void gather_accum_kernel(
    const float* __restrict__ edge_feats, const float* __restrict__ ew,
    const int* __restrict__ src, const int* __restrict__ mirror,
    const int* __restrict__ eidx, const int* __restrict__ binst,
    const int* __restrict__ cnt,
    const float* __restrict__ W_edge, const float* __restrict__ b_edge,
    const float* __restrict__ h, float* __restrict__ out, int N)
{
  const int lane = threadIdx.x & 63;
  const int r16  = lane & 15;
  const int kb   = lane >> 4;
  const int gw   = (int)((blockIdx.x * blockDim.x + threadIdx.x) >> 6);
  const int nw   = (int)((gridDim.x * blockDim.x) >> 6);

  bf16x8 bfr[4][2];
#pragma unroll
  for (int nb = 0; nb < 4; ++nb)
#pragma unroll
    for (int ks = 0; ks < 2; ++ks)
#pragma unroll
      for (int j = 0; j < 8; ++j) {
        const int k = ks * 32 + kb * 8 + j;
        bfr[nb][ks][j] = f2bf(W_edge[k * 64 + nb * 16 + r16]);
      }
  float bb[4];
#pragma unroll
  for (int nb = 0; nb < 4; ++nb) bb[nb] = b_edge[nb * 16 + r16];

  for (int d = gw; d < N; d += nw) {
    const int st = binst[d];
    const int c0 = cnt[d];
    float racc[4] = {0.f, 0.f, 0.f, 0.f};
    const int ntile = (c0 + 15) >> 4;
    for (int t = 0; t < ntile; ++t) {
      const bool val = (t * 16 + r16) < c0;
      const int e = eidx[val ? (st + t * 16 + r16) : st];
      const int sv = src[e];
      const float wv = val ? ew[e] : 0.0f;
      const int mv = mirror[e];

      const float* arow = edge_feats + (size_t)mv * 64 + kb * 8;
      const f32x4 a0 = *(const f32x4*)(arow);
      const f32x4 a1 = *(const f32x4*)(arow + 4);
      const f32x4 a2 = *(const f32x4*)(arow + 32);
      const f32x4 a3 = *(const f32x4*)(arow + 36);

      float ewj[4];
      float hv[4][4];
#pragma unroll
      for (int j = 0; j < 4; ++j) {
        const int row = kb * 4 + j;
        const int sj = __shfl(sv, row, 64);
        ewj[j] = __shfl(wv, row, 64);
        const float* hrow = h + (size_t)sj * 64 + r16;
#pragma unroll
        for (int nb = 0; nb < 4; ++nb) hv[j][nb] = hrow[nb * 16];
      }

      bf16x8 af0, af1;
#pragma unroll
      for (int j = 0; j < 4; ++j) {
        af0[j]     = f2bf(a0[j]);
        af0[j + 4] = f2bf(a1[j]);
        af1[j]     = f2bf(a2[j]);
        af1[j + 4] = f2bf(a3[j]);
      }

      f32x4 c[4];
#pragma unroll
      for (int nb = 0; nb < 4; ++nb) c[nb] = (f32x4){0.f, 0.f, 0.f, 0.f};
#pragma unroll
      for (int nb = 0; nb < 4; ++nb) {
        c[nb] = __builtin_amdgcn_mfma_f32_16x16x32_bf16(af0, bfr[nb][0], c[nb], 0, 0, 0);
        c[nb] = __builtin_amdgcn_mfma_f32_16x16x32_bf16(af1, bfr[nb][1], c[nb], 0, 0, 0);
      }

#pragma unroll
      for (int j = 0; j < 4; ++j) {
#pragma unroll
        for (int nb = 0; nb < 4; ++nb) {
          const float s = c[nb][j] + bb[nb];
          const float p = (1.0f - 2.0f / (__expf(2.0f * s) + 1.0f)) * ewj[j];
          racc[nb] = fmaf(p, hv[j][nb], racc[nb]);
        }
      }
    }
    // reduce across kb groups: all lanes end with full sum for ch nb*16+r16
#pragma unroll
    for (int nb = 0; nb < 4; ++nb) {
      racc[nb] += __shfl_xor(racc[nb], 16, 64);
      racc[nb] += __shfl_xor(racc[nb], 32, 64);
    }
    float v = racc[0];
    if (kb == 1) v = racc[1];
    if (kb == 2) v = racc[2];
    if (kb == 3) v = racc[3];
    out[(size_t)d * 64 + lane] = v;   // ch == lane; full row, no atomics
  }
}

extern "C" void kernel_launch(void* const* d_in, const int* in_sizes, int n_in,
                              void* d_out, int out_size, void* d_ws, size_t ws_size,
                              hipStream_t stream) {
  const float* node_feats   = (const float*)d_in[0];
  const float* edge_feats   = (const float*)d_in[1];
  const float* cond         = (const float*)d_in[2];
  const float* edge_weights = (const float*)d_in[3];
  const int*   src          = (const int*)d_in[4];
  const int*   dst          = (const int*)d_in[5];
  const int*   mirror       = (const int*)d_in[6];
  const float* W_edge       = (const float*)d_in[7];
  const float* b_edge       = (const float*)d_in[8];
  const float* W_cond       = (const float*)d_in[9];
  const float* b_cond       = (const float*)d_in[10];
  const float* W_film       = (const float*)d_in[11];
  const float* b_film       = (const float*)d_in[12];
  const int N = in_sizes[0] / 128;
  const int E = in_sizes[4];

  char* ws = (char*)d_ws;
  float* h     = (float*)ws;                    ws += (size_t)N * 64 * sizeof(float);
  int*   cnt    = (int*)ws;                     ws += (size_t)N * sizeof(int);
  int*   binst  = (int*)ws;                     ws += (size_t)N * sizeof(int);
  int*   cursor = (int*)ws;                     ws += (size_t)N * sizeof(int);
  int*   eidx   = (int*)ws;                     ws += (size_t)E * sizeof(int);

  node_kernel<<<(N + 15) / 16, 192, 0, stream>>>(
      node_feats, cond, W_cond, b_cond, W_film, b_film, h, N);

  hipMemsetAsync(cnt, 0, (size_t)N * sizeof(int), stream);
  hist_kernel<<<1024, 256, 0, stream>>>(dst, cnt, E);
  scan_kernel<<<1, 1024, 0, stream>>>(cnt, binst, cursor, N);
  fill_kernel<<<1024, 256, 0, stream>>>(dst, cursor, eidx, E);
  gather_accum_kernel<<<2048, 256, 0, stream>>>(
      edge_feats, edge_weights, src, mirror, eidx, binst, cnt,
      W_edge, b_edge, h, (float*)d_out, N);
}

// Round 5
// 327.331 us; speedup vs baseline: 2.7318x; 1.3279x over previous
//
#include <hip/hip_runtime.h>
#include <hip/hip_bf16.h>

#define EPSV 1e-5f

typedef __attribute__((ext_vector_type(8))) short bf16x8;
typedef __attribute__((ext_vector_type(4))) float f32x4;

static __device__ __forceinline__ short f2bf(float f) {
  return __builtin_bit_cast(short, __float2bfloat16(f));
}

// ---------------- node pipeline (unchanged) ----------------
__global__ __launch_bounds__(192) void node_kernel(
    const float* __restrict__ node_feats, const float* __restrict__ cond,
    const float* __restrict__ W_cond, const float* __restrict__ b_cond,
    const float* __restrict__ W_film, const float* __restrict__ b_film,
    float* __restrict__ h, int N)
{
  __shared__ __align__(16) float cond_lds[16][256];
  __shared__ __align__(16) float nf_lds[16][128];
  __shared__ __align__(16) float gb_lds[16][128];
  const int t = threadIdx.x;
  const int n0 = blockIdx.x * 16;
  const int rows = min(16, N - n0);

  {
    const float4* c4 = (const float4*)(cond + (size_t)n0 * 256);
    float4* sc = (float4*)&cond_lds[0][0];
    const int climit = rows * 64;
    for (int i = t; i < 16 * 64; i += 192)
      sc[i] = (i < climit) ? c4[i] : make_float4(0.f, 0.f, 0.f, 0.f);
    const float4* n4 = (const float4*)(node_feats + (size_t)n0 * 128);
    float4* sn = (float4*)&nf_lds[0][0];
    const int nlimit = rows * 32;
    for (int i = t; i < 16 * 32; i += 192)
      sn[i] = (i < nlimit) ? n4[i] : make_float4(0.f, 0.f, 0.f, 0.f);
  }
  __syncthreads();

  float acc[16];
  if (t < 128) {
    const float binit = b_cond[t] + (t < 64 ? 1.0f : 0.0f);
#pragma unroll
    for (int j = 0; j < 16; ++j) acc[j] = binit;
    for (int k4 = 0; k4 < 64; ++k4) {
      const float w0 = W_cond[(k4 * 4 + 0) * 128 + t];
      const float w1 = W_cond[(k4 * 4 + 1) * 128 + t];
      const float w2 = W_cond[(k4 * 4 + 2) * 128 + t];
      const float w3 = W_cond[(k4 * 4 + 3) * 128 + t];
#pragma unroll
      for (int j = 0; j < 16; ++j) {
        const float4 v = *(const float4*)&cond_lds[j][k4 * 4];
        acc[j] = fmaf(v.w, w3, fmaf(v.z, w2, fmaf(v.y, w1, fmaf(v.x, w0, acc[j]))));
      }
    }
#pragma unroll
    for (int j = 0; j < 16; ++j) gb_lds[j][t] = acc[j];
  } else {
    const int c = t - 128;
    const float binit = b_film[c];
#pragma unroll
    for (int j = 0; j < 16; ++j) acc[j] = binit;
    for (int k4 = 0; k4 < 32; ++k4) {
      const float w0 = W_film[(k4 * 4 + 0) * 64 + c];
      const float w1 = W_film[(k4 * 4 + 1) * 64 + c];
      const float w2 = W_film[(k4 * 4 + 2) * 64 + c];
      const float w3 = W_film[(k4 * 4 + 3) * 64 + c];
#pragma unroll
      for (int j = 0; j < 16; ++j) {
        const float4 v = *(const float4*)&nf_lds[j][k4 * 4];
        acc[j] = fmaf(v.w, w3, fmaf(v.z, w2, fmaf(v.y, w1, fmaf(v.x, w0, acc[j]))));
      }
    }
#pragma unroll
    for (int j = 0; j < 16; ++j) {
      float s = acc[j];
      float q = acc[j] * acc[j];
#pragma unroll
      for (int off = 32; off >= 1; off >>= 1) {
        s += __shfl_xor(s, off, 64);
        q += __shfl_xor(q, off, 64);
      }
      const float mu = s * (1.0f / 64.0f);
      const float var = q * (1.0f / 64.0f) - mu * mu;
      acc[j] = (acc[j] - mu) * rsqrtf(var + EPSV);
    }
  }
  __syncthreads();
  if (t >= 128) {
    const int c = t - 128;
#pragma unroll
    for (int j = 0; j < 16; ++j) {
      if (j < rows) {
        const float g = gb_lds[j][c];
        const float b = gb_lds[j][64 + c];
        const float hv = fmaf(g, acc[j], b);
        h[(size_t)(n0 + j) * 64 + c] = fmaxf(hv, 0.0f);
      }
    }
  }
}

// ---------------- counting sort by dst + tile list ----------------
__global__ __launch_bounds__(256) void hist_kernel(
    const int* __restrict__ dst, int* __restrict__ cnt, int E)
{
  const int stride = gridDim.x * blockDim.x;
  for (int e = blockIdx.x * blockDim.x + threadIdx.x; e < E; e += stride)
    atomicAdd(&cnt[dst[e]], 1);
}

// phase A: per-block exclusive scan of (cnt, ceil(cnt/16)); in-block prefixes
// to binst/tileoff, block totals to esum/tsum.
__global__ __launch_bounds__(256) void scan_blocks(
    const int* __restrict__ cnt, int* __restrict__ binst, int* __restrict__ tileoff,
    int* __restrict__ esum, int* __restrict__ tsum, int N)
{
  __shared__ int we[4], wt[4];
  const int t = threadIdx.x, lane = t & 63, w = t >> 6;
  const int i = blockIdx.x * 256 + t;
  const int c  = (i < N) ? cnt[i] : 0;
  const int nt = (c + 15) >> 4;
  int pe = c, pt = nt;
#pragma unroll
  for (int off = 1; off < 64; off <<= 1) {
    const int ae = __shfl_up(pe, off, 64);
    const int at = __shfl_up(pt, off, 64);
    if (lane >= off) { pe += ae; pt += at; }
  }
  if (lane == 63) { we[w] = pe; wt[w] = pt; }
  __syncthreads();
  if (t == 0) {
    int re = 0, rt = 0;
#pragma unroll
    for (int k = 0; k < 4; ++k) { const int a = we[k], b = wt[k]; we[k] = re; wt[k] = rt; re += a; rt += b; }
    esum[blockIdx.x] = re;
    tsum[blockIdx.x] = rt;
  }
  __syncthreads();
  if (i < N) {
    binst[i]   = we[w] + pe - c;
    tileoff[i] = wt[w] + pt - nt;
  }
}

// phase B: scan the block totals (NB <= 256), write grand tile total.
__global__ __launch_bounds__(256) void scan_tops(
    int* __restrict__ esum, int* __restrict__ tsum, int* __restrict__ Tcnt, int NB)
{
  __shared__ int we[4], wt[4];
  const int t = threadIdx.x, lane = t & 63, w = t >> 6;
  const int c  = (t < NB) ? esum[t] : 0;
  const int nt = (t < NB) ? tsum[t] : 0;
  int pe = c, pt = nt;
#pragma unroll
  for (int off = 1; off < 64; off <<= 1) {
    const int ae = __shfl_up(pe, off, 64);
    const int at = __shfl_up(pt, off, 64);
    if (lane >= off) { pe += ae; pt += at; }
  }
  if (lane == 63) { we[w] = pe; wt[w] = pt; }
  __syncthreads();
  if (t == 0) {
    int re = 0, rt = 0;
#pragma unroll
    for (int k = 0; k < 4; ++k) { const int a = we[k], b = wt[k]; we[k] = re; wt[k] = rt; re += a; rt += b; }
    Tcnt[0] = rt;   // total tiles
  }
  __syncthreads();
  if (t < NB) {
    esum[t] = we[w] + pe - c;
    tsum[t] = wt[w] + pt - nt;
  }
}

// phase C: add block offsets, init cursor.
__global__ __launch_bounds__(256) void scan_apply(
    int* __restrict__ binst, int* __restrict__ tileoff, int* __restrict__ cursor,
    const int* __restrict__ esum, const int* __restrict__ tsum, int N)
{
  const int i = blockIdx.x * 256 + threadIdx.x;
  if (i < N) {
    const int b = binst[i] + esum[blockIdx.x];
    binst[i] = b;
    cursor[i] = b;
    tileoff[i] += tsum[blockIdx.x];
  }
}

// emit per-tile metadata: tileA = dst | (nvalid<<20), tileB = estart
__global__ __launch_bounds__(256) void emit_tiles(
    const int* __restrict__ cnt, const int* __restrict__ binst,
    const int* __restrict__ tileoff,
    int* __restrict__ tileA, int* __restrict__ tileB, int N)
{
  const int stride = gridDim.x * blockDim.x;
  for (int d = blockIdx.x * blockDim.x + threadIdx.x; d < N; d += stride) {
    const int c = cnt[d];
    const int tb = tileoff[d];
    const int st = binst[d];
    const int nt = (c + 15) >> 4;
    for (int k = 0; k < nt; ++k) {
      tileA[tb + k] = d | (min(16, c - 16 * k) << 20);
      tileB[tb + k] = st + 16 * k;
    }
  }
}

__global__ __launch_bounds__(256) void fill_kernel(
    const int* __restrict__ dst, int* __restrict__ cursor,
    int* __restrict__ eidx, int E)
{
  const int stride = gridDim.x * blockDim.x;
  for (int e = blockIdx.x * blockDim.x + threadIdx.x; e < E; e += stride) {
    const int pos = atomicAdd(&cursor[dst[e]], 1);
    eidx[pos] = e;
  }
}

// ---------------- fused gather-MFMA-accumulate over uniform tiles ----------------
// tile = up to 16 edges sharing one dst. Pad rows point at edge_feats row 0 /
// h row 0 (hot cached) with weight 0. Full cross-row reduce, one 256B
// atomicAdd row per tile.
__global__ __launch_bounds__(256) void gather_tiles_kernel(
    const float* __restrict__ edge_feats, const float* __restrict__ ew,
    const int* __restrict__ src, const int* __restrict__ mirror,
    const int* __restrict__ eidx,
    const int* __restrict__ tileA, const int* __restrict__ tileB,
    const int* __restrict__ Tcnt,
    const float* __restrict__ W_edge, const float* __restrict__ b_edge,
    const float* __restrict__ h, float* __restrict__ out)
{
  const int lane = threadIdx.x & 63;
  const int r16  = lane & 15;
  const int kb   = lane >> 4;
  const int gw   = (int)((blockIdx.x * blockDim.x + threadIdx.x) >> 6);
  const int nw   = (int)((gridDim.x * blockDim.x) >> 6);
  const int T    = Tcnt[0];

  bf16x8 bfr[4][2];
#pragma unroll
  for (int nb = 0; nb < 4; ++nb)
#pragma unroll
    for (int ks = 0; ks < 2; ++ks)
#pragma unroll
      for (int j = 0; j < 8; ++j) {
        const int k = ks * 32 + kb * 8 + j;
        bfr[nb][ks][j] = f2bf(W_edge[k * 64 + nb * 16 + r16]);
      }
  float bb[4];
#pragma unroll
  for (int nb = 0; nb < 4; ++nb) bb[nb] = b_edge[nb * 16 + r16];

  for (int ti = gw; ti < T; ti += nw) {
    const int a  = tileA[ti];
    const int d  = a & 0xFFFFF;
    const int nv = a >> 20;
    const int st = tileB[ti];

    const bool val = r16 < nv;
    const int e  = eidx[st + (val ? r16 : 0)];
    const int sv = val ? src[e] : 0;
    const float wv = val ? ew[e] : 0.0f;
    const int mv = val ? mirror[e] : 0;

    const float* arow = edge_feats + (size_t)mv * 64 + kb * 8;
    const f32x4 a0 = *(const f32x4*)(arow);
    const f32x4 a1 = *(const f32x4*)(arow + 4);
    const f32x4 a2 = *(const f32x4*)(arow + 32);
    const f32x4 a3 = *(const f32x4*)(arow + 36);

    float ewj[4];
    float hv[4][4];
#pragma unroll
    for (int j = 0; j < 4; ++j) {
      const int row = kb * 4 + j;
      const int sj = __shfl(sv, row, 64);
      ewj[j] = __shfl(wv, row, 64);
      const float* hrow = h + (size_t)sj * 64 + r16;
#pragma unroll
      for (int nb = 0; nb < 4; ++nb) hv[j][nb] = hrow[nb * 16];
    }

    bf16x8 af0, af1;
#pragma unroll
    for (int j = 0; j < 4; ++j) {
      af0[j]     = f2bf(a0[j]);
      af0[j + 4] = f2bf(a1[j]);
      af1[j]     = f2bf(a2[j]);
      af1[j + 4] = f2bf(a3[j]);
    }

    f32x4 c[4];
#pragma unroll
    for (int nb = 0; nb < 4; ++nb) c[nb] = (f32x4){0.f, 0.f, 0.f, 0.f};
#pragma unroll
    for (int nb = 0; nb < 4; ++nb) {
      c[nb] = __builtin_amdgcn_mfma_f32_16x16x32_bf16(af0, bfr[nb][0], c[nb], 0, 0, 0);
      c[nb] = __builtin_amdgcn_mfma_f32_16x16x32_bf16(af1, bfr[nb][1], c[nb], 0, 0, 0);
    }

    float racc[4];
#pragma unroll
    for (int nb = 0; nb < 4; ++nb) {
      const float s0 = c[nb][0] + bb[nb];
      const float s1 = c[nb][1] + bb[nb];
      const float s2 = c[nb][2] + bb[nb];
      const float s3 = c[nb][3] + bb[nb];
      float r = (1.0f - 2.0f / (__expf(2.0f * s0) + 1.0f)) * ewj[0] * hv[0][nb];
      r = fmaf((1.0f - 2.0f / (__expf(2.0f * s1) + 1.0f)) * ewj[1], hv[1][nb], r);
      r = fmaf((1.0f - 2.0f / (__expf(2.0f * s2) + 1.0f)) * ewj[2], hv[2][nb], r);
      r = fmaf((1.0f - 2.0f / (__expf(2.0f * s3) + 1.0f)) * ewj[3], hv[3][nb], r);
      r += __shfl_xor(r, 16, 64);
      r += __shfl_xor(r, 32, 64);
      racc[nb] = r;
    }
    float v = racc[0];
    if (kb == 1) v = racc[1];
    if (kb == 2) v = racc[2];
    if (kb == 3) v = racc[3];
    atomicAdd(&out[(size_t)d * 64 + lane], v);
  }
}

extern "C" void kernel_launch(void* const* d_in, const int* in_sizes, int n_in,
                              void* d_out, int out_size, void* d_ws, size_t ws_size,
                              hipStream_t stream) {
  const float* node_feats   = (const float*)d_in[0];
  const float* edge_feats   = (const float*)d_in[1];
  const float* cond         = (const float*)d_in[2];
  const float* edge_weights = (const float*)d_in[3];
  const int*   src          = (const int*)d_in[4];
  const int*   dst          = (const int*)d_in[5];
  const int*   mirror       = (const int*)d_in[6];
  const float* W_edge       = (const float*)d_in[7];
  const float* b_edge       = (const float*)d_in[8];
  const float* W_cond       = (const float*)d_in[9];
  const float* b_cond       = (const float*)d_in[10];
  const float* W_film       = (const float*)d_in[11];
  const float* b_film       = (const float*)d_in[12];
  const int N = in_sizes[0] / 128;
  const int E = in_sizes[4];
  const int NB = (N + 255) / 256;
  const int Tmax = N + E / 16 + 1;

  char* ws = (char*)d_ws;
  float* h      = (float*)ws;  ws += (size_t)N * 64 * sizeof(float);
  int* cnt      = (int*)ws;    ws += (size_t)N * sizeof(int);
  int* binst    = (int*)ws;    ws += (size_t)N * sizeof(int);
  int* tileoff  = (int*)ws;    ws += (size_t)N * sizeof(int);
  int* cursor   = (int*)ws;    ws += (size_t)N * sizeof(int);
  int* eidx     = (int*)ws;    ws += (size_t)E * sizeof(int);
  int* tileA    = (int*)ws;    ws += (size_t)Tmax * sizeof(int);
  int* tileB    = (int*)ws;    ws += (size_t)Tmax * sizeof(int);
  int* esum     = (int*)ws;    ws += 256 * sizeof(int);
  int* tsum     = (int*)ws;    ws += 256 * sizeof(int);
  int* Tcnt     = (int*)ws;    ws += sizeof(int);

  node_kernel<<<(N + 15) / 16, 192, 0, stream>>>(
      node_feats, cond, W_cond, b_cond, W_film, b_film, h, N);

  hipMemsetAsync(cnt, 0, (size_t)N * sizeof(int), stream);
  hipMemsetAsync(d_out, 0, (size_t)out_size * sizeof(float), stream);
  hist_kernel<<<1024, 256, 0, stream>>>(dst, cnt, E);
  scan_blocks<<<NB, 256, 0, stream>>>(cnt, binst, tileoff, esum, tsum, N);
  scan_tops<<<1, 256, 0, stream>>>(esum, tsum, Tcnt, NB);
  scan_apply<<<NB, 256, 0, stream>>>(binst, tileoff, cursor, esum, tsum, N);
  emit_tiles<<<256, 256, 0, stream>>>(cnt, binst, tileoff, tileA, tileB, N);
  fill_kernel<<<1024, 256, 0, stream>>>(dst, cursor, eidx, E);
  gather_tiles_kernel<<<2048, 256, 0, stream>>>(
      edge_feats, edge_weights, src, mirror, eidx, tileA, tileB, Tcnt,
      W_edge, b_edge, h, (float*)d_out);
}

// Round 6
// 256.024 us; speedup vs baseline: 3.4926x; 1.2785x over previous
//
#include <hip/hip_runtime.h>
#include <hip/hip_bf16.h>

#define EPSV 1e-5f

typedef __attribute__((ext_vector_type(8))) short bf16x8;
typedef __attribute__((ext_vector_type(4))) float f32x4;

static __device__ __forceinline__ short f2bf(float f) {
  return __builtin_bit_cast(short, __float2bfloat16(f));
}

// ---------------- node pipeline: MFMA ----------------
// gb = cond @ W_cond + b_cond (gamma+1), h0 = nf @ W_film + b_film,
// h = relu(gamma * LN(h0) + beta).  4 waves/block; wave w owns gb cols
// [w*32,w*32+32) and h0 cols [w*16,w*16+16); B-frags in VGPRs once per wave.
__global__ __launch_bounds__(256) void node_mfma_kernel(
    const float* __restrict__ node_feats, const float* __restrict__ cond,
    const float* __restrict__ W_cond, const float* __restrict__ b_cond,
    const float* __restrict__ W_film, const float* __restrict__ b_film,
    float* __restrict__ h, int N)
{
  __shared__ __align__(16) short cond_s[16][264];  // bf16, stride 132 dw (≡4 mod 32)
  __shared__ __align__(16) short nf_s[16][136];    // stride 68 dw (≡4 mod 32)
  __shared__ __align__(16) float gb_s[16][132];
  __shared__ __align__(16) float h_s[16][68];

  const int t = threadIdx.x;
  const int lane = t & 63;
  const int w = t >> 6;
  const int r16 = lane & 15;
  const int kb = lane >> 4;

  // one-time B fragments (lane l holds B[k=kb*8+j][col], k-block ks)
  const int colc0 = w * 32 + r16;
  const int colc1 = w * 32 + 16 + r16;
  bf16x8 bc[2][8];
#pragma unroll
  for (int ks = 0; ks < 8; ++ks)
#pragma unroll
    for (int j = 0; j < 8; ++j) {
      const int k = ks * 32 + kb * 8 + j;
      bc[0][ks][j] = f2bf(W_cond[k * 128 + colc0]);
      bc[1][ks][j] = f2bf(W_cond[k * 128 + colc1]);
    }
  const int colf = w * 16 + r16;
  bf16x8 bfm[4];
#pragma unroll
  for (int ks = 0; ks < 4; ++ks)
#pragma unroll
    for (int j = 0; j < 8; ++j)
      bfm[ks][j] = f2bf(W_film[(ks * 32 + kb * 8 + j) * 64 + colf]);
  const float bbc0 = b_cond[colc0] + (w < 2 ? 1.0f : 0.0f);
  const float bbc1 = b_cond[colc1] + (w < 2 ? 1.0f : 0.0f);
  const float bbf = b_film[colf];

  const int ntiles = (N + 15) >> 4;
  for (int tile = blockIdx.x; tile < ntiles; tile += gridDim.x) {
    const int n0 = tile << 4;
    const int rows = min(16, N - n0);
    { // stage cond (16x256) + nf (16x128) as bf16
      const float4* c4 = (const float4*)(cond + (size_t)n0 * 256);
#pragma unroll
      for (int it = 0; it < 4; ++it) {
        const int i = t + it * 256;
        const int row = i >> 6, c = i & 63;
        const float4 v = (row < rows) ? c4[i] : make_float4(0.f, 0.f, 0.f, 0.f);
        short* p = &cond_s[row][c * 4];
        p[0] = f2bf(v.x); p[1] = f2bf(v.y); p[2] = f2bf(v.z); p[3] = f2bf(v.w);
      }
      const float4* n4 = (const float4*)(node_feats + (size_t)n0 * 128);
#pragma unroll
      for (int it = 0; it < 2; ++it) {
        const int i = t + it * 256;
        const int row = i >> 5, c = i & 31;
        const float4 v = (row < rows) ? n4[i] : make_float4(0.f, 0.f, 0.f, 0.f);
        short* p = &nf_s[row][c * 4];
        p[0] = f2bf(v.x); p[1] = f2bf(v.y); p[2] = f2bf(v.z); p[3] = f2bf(v.w);
      }
    }
    __syncthreads();

    f32x4 cg0 = {0.f, 0.f, 0.f, 0.f}, cg1 = {0.f, 0.f, 0.f, 0.f};
#pragma unroll
    for (int ks = 0; ks < 8; ++ks) {
      const bf16x8 a = *(const bf16x8*)&cond_s[r16][ks * 32 + kb * 8];
      cg0 = __builtin_amdgcn_mfma_f32_16x16x32_bf16(a, bc[0][ks], cg0, 0, 0, 0);
      cg1 = __builtin_amdgcn_mfma_f32_16x16x32_bf16(a, bc[1][ks], cg1, 0, 0, 0);
    }
    f32x4 ch = {0.f, 0.f, 0.f, 0.f};
#pragma unroll
    for (int ks = 0; ks < 4; ++ks) {
      const bf16x8 a = *(const bf16x8*)&nf_s[r16][ks * 32 + kb * 8];
      ch = __builtin_amdgcn_mfma_f32_16x16x32_bf16(a, bfm[ks], ch, 0, 0, 0);
    }
    // C layout: row = kb*4+j, col = frag col
#pragma unroll
    for (int j = 0; j < 4; ++j) {
      gb_s[kb * 4 + j][colc0] = cg0[j] + bbc0;
      gb_s[kb * 4 + j][colc1] = cg1[j] + bbc1;
      h_s[kb * 4 + j][colf]   = ch[j] + bbf;
    }
    __syncthreads();

    // LN + FiLM + relu: wave w handles rows w*4..w*4+3, lane = channel
#pragma unroll
    for (int rr = 0; rr < 4; ++rr) {
      const int r = w * 4 + rr;
      const float v = h_s[r][lane];
      float s = v, q = v * v;
#pragma unroll
      for (int off = 1; off < 64; off <<= 1) {
        s += __shfl_xor(s, off, 64);
        q += __shfl_xor(q, off, 64);
      }
      const float mu = s * (1.0f / 64.0f);
      const float var = q * (1.0f / 64.0f) - mu * mu;
      const float hn = (v - mu) * rsqrtf(var + EPSV);
      const float gm = gb_s[r][lane];
      const float bt = gb_s[r][64 + lane];
      if (r < rows)
        h[(size_t)(n0 + r) * 64 + lane] = fmaxf(fmaf(gm, hn, bt), 0.0f);
    }
    // no barrier needed here: next stage writes cond_s/nf_s only; gb_s/h_s
    // rewrites happen after the next __syncthreads.
  }
}

// ---------------- counting sort by dst + tile list ----------------
__global__ __launch_bounds__(256) void hist_kernel(
    const int* __restrict__ dst, int* __restrict__ cnt, int E)
{
  const int stride = gridDim.x * blockDim.x;
  for (int e = blockIdx.x * blockDim.x + threadIdx.x; e < E; e += stride)
    atomicAdd(&cnt[dst[e]], 1);
}

__global__ __launch_bounds__(256) void scan_blocks(
    const int* __restrict__ cnt, int* __restrict__ binst, int* __restrict__ tileoff,
    int* __restrict__ esum, int* __restrict__ tsum, int N)
{
  __shared__ int we[4], wt[4];
  const int t = threadIdx.x, lane = t & 63, w = t >> 6;
  const int i = blockIdx.x * 256 + t;
  const int c  = (i < N) ? cnt[i] : 0;
  const int nt = (c + 15) >> 4;
  int pe = c, pt = nt;
#pragma unroll
  for (int off = 1; off < 64; off <<= 1) {
    const int ae = __shfl_up(pe, off, 64);
    const int at = __shfl_up(pt, off, 64);
    if (lane >= off) { pe += ae; pt += at; }
  }
  if (lane == 63) { we[w] = pe; wt[w] = pt; }
  __syncthreads();
  if (t == 0) {
    int re = 0, rt = 0;
#pragma unroll
    for (int k = 0; k < 4; ++k) { const int a = we[k], b = wt[k]; we[k] = re; wt[k] = rt; re += a; rt += b; }
    esum[blockIdx.x] = re;
    tsum[blockIdx.x] = rt;
  }
  __syncthreads();
  if (i < N) {
    binst[i]   = we[w] + pe - c;
    tileoff[i] = wt[w] + pt - nt;
  }
}

__global__ __launch_bounds__(256) void scan_tops(
    int* __restrict__ esum, int* __restrict__ tsum, int* __restrict__ Tcnt, int NB)
{
  __shared__ int we[4], wt[4];
  const int t = threadIdx.x, lane = t & 63, w = t >> 6;
  const int c  = (t < NB) ? esum[t] : 0;
  const int nt = (t < NB) ? tsum[t] : 0;
  int pe = c, pt = nt;
#pragma unroll
  for (int off = 1; off < 64; off <<= 1) {
    const int ae = __shfl_up(pe, off, 64);
    const int at = __shfl_up(pt, off, 64);
    if (lane >= off) { pe += ae; pt += at; }
  }
  if (lane == 63) { we[w] = pe; wt[w] = pt; }
  __syncthreads();
  if (t == 0) {
    int re = 0, rt = 0;
#pragma unroll
    for (int k = 0; k < 4; ++k) { const int a = we[k], b = wt[k]; we[k] = re; wt[k] = rt; re += a; rt += b; }
    Tcnt[0] = rt;
  }
  __syncthreads();
  if (t < NB) {
    esum[t] = we[w] + pe - c;
    tsum[t] = wt[w] + pt - nt;
  }
}

__global__ __launch_bounds__(256) void scan_apply(
    int* __restrict__ binst, int* __restrict__ tileoff, int* __restrict__ cursor,
    const int* __restrict__ esum, const int* __restrict__ tsum, int N)
{
  const int i = blockIdx.x * 256 + threadIdx.x;
  if (i < N) {
    const int b = binst[i] + esum[blockIdx.x];
    binst[i] = b;
    cursor[i] = b;
    tileoff[i] += tsum[blockIdx.x];
  }
}

__global__ __launch_bounds__(256) void emit_tiles(
    const int* __restrict__ cnt, const int* __restrict__ binst,
    const int* __restrict__ tileoff,
    int* __restrict__ tileA, int* __restrict__ tileB, int N)
{
  const int stride = gridDim.x * blockDim.x;
  for (int d = blockIdx.x * blockDim.x + threadIdx.x; d < N; d += stride) {
    const int c = cnt[d];
    const int tb = tileoff[d];
    const int st = binst[d];
    const int nt = (c + 15) >> 4;
    for (int k = 0; k < nt; ++k) {
      tileA[tb + k] = d | (min(16, c - 16 * k) << 20);
      tileB[tb + k] = st + 16 * k;
    }
  }
}

__global__ __launch_bounds__(256) void fill_kernel(
    const int* __restrict__ dst, int* __restrict__ cursor,
    int* __restrict__ eidx, int E)
{
  const int stride = gridDim.x * blockDim.x;
  for (int e = blockIdx.x * blockDim.x + threadIdx.x; e < E; e += stride) {
    const int pos = atomicAdd(&cursor[dst[e]], 1);
    eidx[pos] = e;
  }
}

// ---------------- fused gather-MFMA-accumulate over uniform tiles ----------------
__global__ __launch_bounds__(256) void gather_tiles_kernel(
    const float* __restrict__ edge_feats, const float* __restrict__ ew,
    const int* __restrict__ src, const int* __restrict__ mirror,
    const int* __restrict__ eidx,
    const int* __restrict__ tileA, const int* __restrict__ tileB,
    const int* __restrict__ Tcnt,
    const float* __restrict__ W_edge, const float* __restrict__ b_edge,
    const float* __restrict__ h, float* __restrict__ out)
{
  const int lane = threadIdx.x & 63;
  const int r16  = lane & 15;
  const int kb   = lane >> 4;
  const int gw   = (int)((blockIdx.x * blockDim.x + threadIdx.x) >> 6);
  const int nw   = (int)((gridDim.x * blockDim.x) >> 6);
  const int T    = Tcnt[0];

  bf16x8 bfr[4][2];
#pragma unroll
  for (int nb = 0; nb < 4; ++nb)
#pragma unroll
    for (int ks = 0; ks < 2; ++ks)
#pragma unroll
      for (int j = 0; j < 8; ++j) {
        const int k = ks * 32 + kb * 8 + j;
        bfr[nb][ks][j] = f2bf(W_edge[k * 64 + nb * 16 + r16]);
      }
  float bb[4];
#pragma unroll
  for (int nb = 0; nb < 4; ++nb) bb[nb] = b_edge[nb * 16 + r16];

  for (int ti = gw; ti < T; ti += nw) {
    const int a  = tileA[ti];
    const int d  = a & 0xFFFFF;
    const int nv = a >> 20;
    const int st = tileB[ti];

    const bool val = r16 < nv;
    const int e  = eidx[st + (val ? r16 : 0)];
    const int sv = val ? src[e] : 0;
    const float wv = val ? ew[e] : 0.0f;
    const int mv = val ? mirror[e] : 0;

    const float* arow = edge_feats + (size_t)mv * 64 + kb * 8;
    const f32x4 a0 = *(const f32x4*)(arow);
    const f32x4 a1 = *(const f32x4*)(arow + 4);
    const f32x4 a2 = *(const f32x4*)(arow + 32);
    const f32x4 a3 = *(const f32x4*)(arow + 36);

    float ewj[4];
    float hv[4][4];
#pragma unroll
    for (int j = 0; j < 4; ++j) {
      const int row = kb * 4 + j;
      const int sj = __shfl(sv, row, 64);
      ewj[j] = __shfl(wv, row, 64);
      const float* hrow = h + (size_t)sj * 64 + r16;
#pragma unroll
      for (int nb = 0; nb < 4; ++nb) hv[j][nb] = hrow[nb * 16];
    }

    bf16x8 af0, af1;
#pragma unroll
    for (int j = 0; j < 4; ++j) {
      af0[j]     = f2bf(a0[j]);
      af0[j + 4] = f2bf(a1[j]);
      af1[j]     = f2bf(a2[j]);
      af1[j + 4] = f2bf(a3[j]);
    }

    f32x4 c[4];
#pragma unroll
    for (int nb = 0; nb < 4; ++nb) c[nb] = (f32x4){0.f, 0.f, 0.f, 0.f};
#pragma unroll
    for (int nb = 0; nb < 4; ++nb) {
      c[nb] = __builtin_amdgcn_mfma_f32_16x16x32_bf16(af0, bfr[nb][0], c[nb], 0, 0, 0);
      c[nb] = __builtin_amdgcn_mfma_f32_16x16x32_bf16(af1, bfr[nb][1], c[nb], 0, 0, 0);
    }

    float racc[4];
#pragma unroll
    for (int nb = 0; nb < 4; ++nb) {
      const float s0 = c[nb][0] + bb[nb];
      const float s1 = c[nb][1] + bb[nb];
      const float s2 = c[nb][2] + bb[nb];
      const float s3 = c[nb][3] + bb[nb];
      float r = (1.0f - 2.0f / (__expf(2.0f * s0) + 1.0f)) * ewj[0] * hv[0][nb];
      r = fmaf((1.0f - 2.0f / (__expf(2.0f * s1) + 1.0f)) * ewj[1], hv[1][nb], r);
      r = fmaf((1.0f - 2.0f / (__expf(2.0f * s2) + 1.0f)) * ewj[2], hv[2][nb], r);
      r = fmaf((1.0f - 2.0f / (__expf(2.0f * s3) + 1.0f)) * ewj[3], hv[3][nb], r);
      r += __shfl_xor(r, 16, 64);
      r += __shfl_xor(r, 32, 64);
      racc[nb] = r;
    }
    float v = racc[0];
    if (kb == 1) v = racc[1];
    if (kb == 2) v = racc[2];
    if (kb == 3) v = racc[3];
    atomicAdd(&out[(size_t)d * 64 + lane], v);
  }
}

extern "C" void kernel_launch(void* const* d_in, const int* in_sizes, int n_in,
                              void* d_out, int out_size, void* d_ws, size_t ws_size,
                              hipStream_t stream) {
  const float* node_feats   = (const float*)d_in[0];
  const float* edge_feats   = (const float*)d_in[1];
  const float* cond         = (const float*)d_in[2];
  const float* edge_weights = (const float*)d_in[3];
  const int*   src          = (const int*)d_in[4];
  const int*   dst          = (const int*)d_in[5];
  const int*   mirror       = (const int*)d_in[6];
  const float* W_edge       = (const float*)d_in[7];
  const float* b_edge       = (const float*)d_in[8];
  const float* W_cond       = (const float*)d_in[9];
  const float* b_cond       = (const float*)d_in[10];
  const float* W_film       = (const float*)d_in[11];
  const float* b_film       = (const float*)d_in[12];
  const int N = in_sizes[0] / 128;
  const int E = in_sizes[4];
  const int NB = (N + 255) / 256;
  const int Tmax = N + E / 16 + 1;

  char* ws = (char*)d_ws;
  float* h      = (float*)ws;  ws += (size_t)N * 64 * sizeof(float);
  int* cnt      = (int*)ws;    ws += (size_t)N * sizeof(int);
  int* binst    = (int*)ws;    ws += (size_t)N * sizeof(int);
  int* tileoff  = (int*)ws;    ws += (size_t)N * sizeof(int);
  int* cursor   = (int*)ws;    ws += (size_t)N * sizeof(int);
  int* eidx     = (int*)ws;    ws += (size_t)E * sizeof(int);
  int* tileA    = (int*)ws;    ws += (size_t)Tmax * sizeof(int);
  int* tileB    = (int*)ws;    ws += (size_t)Tmax * sizeof(int);
  int* esum     = (int*)ws;    ws += 256 * sizeof(int);
  int* tsum     = (int*)ws;    ws += 256 * sizeof(int);
  int* Tcnt     = (int*)ws;    ws += sizeof(int);

  node_mfma_kernel<<<1024, 256, 0, stream>>>(
      node_feats, cond, W_cond, b_cond, W_film, b_film, h, N);

  hipMemsetAsync(cnt, 0, (size_t)N * sizeof(int), stream);
  hipMemsetAsync(d_out, 0, (size_t)out_size * sizeof(float), stream);
  hist_kernel<<<1024, 256, 0, stream>>>(dst, cnt, E);
  scan_blocks<<<NB, 256, 0, stream>>>(cnt, binst, tileoff, esum, tsum, N);
  scan_tops<<<1, 256, 0, stream>>>(esum, tsum, Tcnt, NB);
  scan_apply<<<NB, 256, 0, stream>>>(binst, tileoff, cursor, esum, tsum, N);
  emit_tiles<<<256, 256, 0, stream>>>(cnt, binst, tileoff, tileA, tileB, N);
  fill_kernel<<<1024, 256, 0, stream>>>(dst, cursor, eidx, E);
  gather_tiles_kernel<<<2048, 256, 0, stream>>>(
      edge_feats, edge_weights, src, mirror, eidx, tileA, tileB, Tcnt,
      W_edge, b_edge, h, (float*)d_out);
}